// Round 4
// baseline (1091.371 us; speedup 1.0000x reference)
//
#include <hip/hip_runtime.h>

// QORNN v4: 4 independent batch rows per 1024-thread workgroup (grid=64).
// r3 evidence: step ~860cy but per-wave VALU issue only ~220cy -> kernel is
// serial-latency-bound at 1 wave/SIMD (Occupancy 11.7%). Rows are independent,
// so co-scheduling 4 rows' waves on each SIMD hides barrier/LDS/dep-chain
// latency with other rows' sdot issue. Per-row structure unchanged from v3
// (quad k-split + DPP butterfly + lane-specialized exact modrelu).
// x staged in 64-step double-buffered chunks (4KB/row/buf) in reused LDS,
// staggered per row-group (s == 8g) so HBM stalls of one group overlap with
// compute of the others.

#define TSEQ 1024
#define IDIM 64
#define HDIM 256
#define ODIM 16
#define RPW 4                   // rows per workgroup
#define CHUNK 64                // steps per x chunk
#define NCHUNK (TSEQ / CHUNK)

__device__ __forceinline__ int sdot4i8(int a, int b, int c) {
#if __has_builtin(__builtin_amdgcn_sdot4)
    return __builtin_amdgcn_sdot4(a, b, c, false);
#else
    int r = c;
    r += ((a << 24) >> 24) * ((b << 24) >> 24);
    r += ((a << 16) >> 24) * ((b << 16) >> 24);
    r += ((a << 8)  >> 24) * ((b << 8)  >> 24);
    r += (a >> 24) * (b >> 24);
    return r;
#endif
}

__device__ __forceinline__ int qpack4(float4 f, float s, float lo, float hi) {
    int a = (int)fminf(fmaxf(rintf(f.x * s), lo), hi);
    int b = (int)fminf(fmaxf(rintf(f.y * s), lo), hi);
    int c = (int)fminf(fmaxf(rintf(f.z * s), lo), hi);
    int d = (int)fminf(fmaxf(rintf(f.w * s), lo), hi);
    return (a & 255) | ((b & 255) << 8) | ((c & 255) << 16) | ((d & 255) << 24);
}

// quad butterfly sum: all 4 lanes of each quad end with the quad-sum
__device__ __forceinline__ int qsum(int v) {
    v += __builtin_amdgcn_update_dpp(0, v, 0xB1, 0xF, 0xF, true); // quad_perm xor1
    v += __builtin_amdgcn_update_dpp(0, v, 0x4E, 0xF, 0xF, true); // quad_perm xor2
    return v;
}

__global__ __launch_bounds__(1024, 1)
void qornn_kernel(const float* __restrict__ x, const float* __restrict__ Wi,
                  const float* __restrict__ Wr, const float* __restrict__ Wo,
                  const float* __restrict__ bias, float* __restrict__ out) {
    // wstage: 32KB — weight staging during init, then x chunks: 4 groups x 2 bufs x 1024 dwords
    __shared__ alignas(16) int wstage[8192];
    __shared__ alignas(16) int wo_lds[1024];              // Wo int8, resident (4KB)
    __shared__ alignas(16) int hbuf[RPW][2][64];          // per-row double-buffered h

    const int tid  = threadIdx.x;       // 0..1023
    const int g    = tid >> 8;          // row group 0..3
    const int t256 = tid & 255;         // thread within group == output index
    const int l    = t256 & 63;
    const int q    = l & 3;             // k-quarter; also output slot within quad
    const int obase = (t256 >> 6) * 64 + (l >> 2) * 4;    // obase + q == t256

    // ---- stage Wi [256x64] -> int8 (scale 8); each lane keeps 4 quarter-rows ----
    {
        const float4* wi4 = (const float4*)Wi;
        #pragma unroll
        for (int it = 0; it < 4; ++it) {
            int flat = it * 1024 + tid;                   // dwords 0..4095
            wstage[flat] = qpack4(wi4[flat], 8.0f, -8.0f, 7.0f);
        }
    }
    __syncthreads();
    int4 wiq[4];   // wiq[i] = Wi[obase+i][q*16 .. +15]
    {
        const int4* p = (const int4*)wstage;
        #pragma unroll
        for (int i = 0; i < 4; ++i) wiq[i] = p[(obase + i) * 4 + q];
    }
    __syncthreads();

    // ---- stage Wr [256x256] -> int8 in two 128-row halves; lane keeps 4 quarter-rows ----
    int4 wr[16];   // wr[i*4+r] = Wr[obase+i][q*64 + r*16 .. +15]
    {
        const float4* wr4 = (const float4*)Wr;
        #pragma unroll
        for (int half = 0; half < 2; ++half) {
            #pragma unroll
            for (int it = 0; it < 8; ++it) {
                int flat = it * 1024 + tid;               // dwords 0..8191
                wstage[flat] = qpack4(wr4[half * 8192 + flat], 8.0f, -8.0f, 7.0f);
            }
            __syncthreads();
            if ((obase >> 7) == half) {
                const int4* p = (const int4*)wstage;      // 16 int4 per row
                const int ob = obase & 127;
                #pragma unroll
                for (int i = 0; i < 4; ++i)
                    #pragma unroll
                    for (int r = 0; r < 4; ++r)
                        wr[i * 4 + r] = p[(ob + i) * 16 + q * 4 + r];
            }
            __syncthreads();
        }
    }

    // ---- stage Wo [16x256] -> int8, resident ----
    {
        const float4* wo4 = (const float4*)Wo;
        wo_lds[tid] = qpack4(wo4[tid], 8.0f, -8.0f, 7.0f);
    }

    // ---- x chunk 0 for this row; h0 = 0 ----
    const int row = blockIdx.x * RPW + g;
    const float4* rowf4 = (const float4*)(x + (size_t)row * (TSEQ * IDIM));
    int* xg = wstage + g * 2048;                          // this group's 2 chunk buffers
    {
        #pragma unroll
        for (int it = 0; it < 4; ++it) {
            int idx = it * 256 + t256;                    // float4 idx within chunk 0
            xg[idx] = qpack4(rowf4[idx], 128.0f, -128.0f, 127.0f);
        }
    }
    if (t256 < 64) hbuf[g][0][t256] = 0;
    const float bv = bias[t256];
    const bool qb0 = (q & 1) != 0;
    const bool qb1 = (q & 2) != 0;
    __syncthreads();

    // u accumulators for t=0
    int u[4];
    {
        const int4 xx = *(const int4*)(xg + q * 4);
        #pragma unroll
        for (int i = 0; i < 4; ++i) {
            int s = sdot4i8(xx.x, wiq[i].x, 0);
            s = sdot4i8(xx.y, wiq[i].y, s);
            s = sdot4i8(xx.z, wiq[i].z, s);
            u[i] = sdot4i8(xx.w, wiq[i].w, s);
        }
    }

    // ---- main recurrence: 1024 steps, 1 barrier/step ----
    for (int t = 0; t < TSEQ; ++t) {
        // staggered chunk staging: group g stages chunk (t>>6)+1 at s == 8g
        if ((t & (CHUNK - 1)) == (g << 3) && t < TSEQ - CHUNK) {
            const int nc = (t >> 6) + 1;
            int* dst = xg + (nc & 1) * 1024;
            #pragma unroll
            for (int it = 0; it < 4; ++it) {
                int idx = it * 256 + t256;
                dst[idx] = qpack4(rowf4[nc * 1024 + idx], 128.0f, -128.0f, 127.0f);
            }
        }

        // this lane's k-quarter of h_t
        int4 hh[4];
        {
            const int4* hP = (const int4*)hbuf[g][t & 1];
            #pragma unroll
            for (int r = 0; r < 4; ++r) hh[r] = hP[q * 4 + r];
        }
        // next step's x quarter (wrapped at t=1023; value unused then)
        const int tt = (t + 1) & (TSEQ - 1);
        const int4 xn = *(const int4*)(xg + ((tt >> 6) & 1) * 1024 + (tt & 63) * 16 + q * 4);

        // z partials: two chains per output, seeded with u[i]
        int za[4], zb[4];
        #pragma unroll
        for (int i = 0; i < 4; ++i) {
            int s0 = u[i];
            s0 = sdot4i8(hh[0].x, wr[i * 4 + 0].x, s0);
            s0 = sdot4i8(hh[0].y, wr[i * 4 + 0].y, s0);
            s0 = sdot4i8(hh[0].z, wr[i * 4 + 0].z, s0);
            s0 = sdot4i8(hh[0].w, wr[i * 4 + 0].w, s0);
            s0 = sdot4i8(hh[1].x, wr[i * 4 + 1].x, s0);
            s0 = sdot4i8(hh[1].y, wr[i * 4 + 1].y, s0);
            s0 = sdot4i8(hh[1].z, wr[i * 4 + 1].z, s0);
            s0 = sdot4i8(hh[1].w, wr[i * 4 + 1].w, s0);
            int s1 = 0;
            s1 = sdot4i8(hh[2].x, wr[i * 4 + 2].x, s1);
            s1 = sdot4i8(hh[2].y, wr[i * 4 + 2].y, s1);
            s1 = sdot4i8(hh[2].z, wr[i * 4 + 2].z, s1);
            s1 = sdot4i8(hh[2].w, wr[i * 4 + 2].w, s1);
            s1 = sdot4i8(hh[3].x, wr[i * 4 + 3].x, s1);
            s1 = sdot4i8(hh[3].y, wr[i * 4 + 3].y, s1);
            s1 = sdot4i8(hh[3].z, wr[i * 4 + 3].z, s1);
            s1 = sdot4i8(hh[3].w, wr[i * 4 + 3].w, s1);
            za[i] = s0; zb[i] = s1;
        }
        // u for t+1 (h-independent; fills latency bubbles)
        int un[4];
        #pragma unroll
        for (int i = 0; i < 4; ++i) {
            int s = sdot4i8(xn.x, wiq[i].x, 0);
            s = sdot4i8(xn.y, wiq[i].y, s);
            s = sdot4i8(xn.z, wiq[i].z, s);
            un[i] = sdot4i8(xn.w, wiq[i].w, s);
        }

        // quad-reduce 4 outputs; lane q keeps output obase+q (== t256)
        const int z0 = qsum(za[0] + zb[0]);
        const int z1 = qsum(za[1] + zb[1]);
        const int z2 = qsum(za[2] + zb[2]);
        const int z3 = qsum(za[3] + zb[3]);
        const int zlo = qb0 ? z1 : z0;
        const int zhi = qb0 ? z3 : z2;
        const int z   = qb1 ? zhi : zlo;

        // exact modrelu + 8-bit requantize (fp32 rounding identical to ref)
        const float zf = (float)z;
        const float t1 = fmaf(fabsf(zf), 0.0009765625f, bv);
        const float t2 = fmaxf(t1, 0.0f);
        const float r  = rintf(t2 * 128.0f);
        const int vpos = (int)fminf(r, 127.0f);
        const int vneg = -(int)fminf(r, 128.0f);
        int hv = (z < 0) ? vneg : vpos;
        hv = (z == 0) ? 0 : hv;

        ((signed char*)hbuf[g][(t + 1) & 1])[t256] = (signed char)hv;

        #pragma unroll
        for (int i = 0; i < 4; ++i) u[i] = un[i];
        __syncthreads();
    }

    // ---- epilogue: out[row, o] = h_1024 . Wo_row(o) / 1024 (h_1024 in hbuf[g][0]) ----
    if (t256 < ODIM) {
        const int4* wo = (const int4*)wo_lds;
        const int4* hl = (const int4*)hbuf[g][0];
        int a0 = 0, a1 = 0, a2 = 0, a3 = 0;
        #pragma unroll
        for (int i = 0; i < 16; ++i) {
            int4 w4 = wo[t256 * 16 + i];
            int4 h4 = hl[i];
            a0 = sdot4i8(h4.x, w4.x, a0);
            a1 = sdot4i8(h4.y, w4.y, a1);
            a2 = sdot4i8(h4.z, w4.z, a2);
            a3 = sdot4i8(h4.w, w4.w, a3);
        }
        out[row * ODIM + t256] = (float)((a0 + a1) + (a2 + a3)) * 0.0009765625f;
    }
}

extern "C" void kernel_launch(void* const* d_in, const int* in_sizes, int n_in,
                              void* d_out, int out_size, void* d_ws, size_t ws_size,
                              hipStream_t stream) {
    const float* x  = (const float*)d_in[0];   // [B, T, I]
    const float* Wi = (const float*)d_in[1];   // [H, I]
    const float* Wr = (const float*)d_in[2];   // [H, H]
    const float* Wo = (const float*)d_in[3];   // [O, H]
    const float* b  = (const float*)d_in[4];   // [H]
    float* out = (float*)d_out;                // [B, O]

    const int B = in_sizes[0] / (TSEQ * IDIM); // 256
    qornn_kernel<<<B / RPW, RPW * 256, 0, stream>>>(x, Wi, Wr, Wo, b, out);
}

// Round 5
// 513.764 us; speedup vs baseline: 2.1243x; 2.1243x over previous
//
#include <hip/hip_runtime.h>

// QORNN v5: 1 row per 512-thread workgroup (grid=256, all CUs), 2 waves/SIMD.
// v4 post-mortem: 1024-thr blocks used only 64 CUs AND compiler capped VGPRs
// at 64 -> weight spills (FETCH 34->53MB, VALUBusy 21%). v5 keeps v3's proven
// structure (full-x-in-LDS, quad k-split, DPP reduce, exact int math) but
// halves per-lane work: each quad owns 2 outputs (32+8 sdots/lane, ~44
// persistent weight VGPRs), so 8 waves/block co-schedule 2/SIMD and fill each
// other's barrier/LDS-latency/dep-chain bubbles. __launch_bounds__(512,2)
// -> 256-VGPR cap, no spill.

#define TSEQ 1024
#define IDIM 64
#define HDIM 256
#define ODIM 16

__device__ __forceinline__ int sdot4i8(int a, int b, int c) {
#if __has_builtin(__builtin_amdgcn_sdot4)
    return __builtin_amdgcn_sdot4(a, b, c, false);
#else
    int r = c;
    r += ((a << 24) >> 24) * ((b << 24) >> 24);
    r += ((a << 16) >> 24) * ((b << 16) >> 24);
    r += ((a << 8)  >> 24) * ((b << 8)  >> 24);
    r += (a >> 24) * (b >> 24);
    return r;
#endif
}

__device__ __forceinline__ int qpack4(float4 f, float s, float lo, float hi) {
    int a = (int)fminf(fmaxf(rintf(f.x * s), lo), hi);
    int b = (int)fminf(fmaxf(rintf(f.y * s), lo), hi);
    int c = (int)fminf(fmaxf(rintf(f.z * s), lo), hi);
    int d = (int)fminf(fmaxf(rintf(f.w * s), lo), hi);
    return (a & 255) | ((b & 255) << 8) | ((c & 255) << 16) | ((d & 255) << 24);
}

// quad butterfly sum: all 4 lanes of each quad end with the quad-sum
__device__ __forceinline__ int qsum(int v) {
    v += __builtin_amdgcn_update_dpp(0, v, 0xB1, 0xF, 0xF, true); // quad_perm xor1
    v += __builtin_amdgcn_update_dpp(0, v, 0x4E, 0xF, 0xF, true); // quad_perm xor2
    return v;
}

__global__ __launch_bounds__(512, 2)
void qornn_kernel(const float* __restrict__ x, const float* __restrict__ Wi,
                  const float* __restrict__ Wr, const float* __restrict__ Wo,
                  const float* __restrict__ bias, float* __restrict__ out) {
    __shared__ alignas(16) int xlds[TSEQ * 16 + 16]; // whole row int8-packed (64KB+pad)
    __shared__ alignas(16) int wstage[8192];         // 32KB weight staging
    __shared__ alignas(16) int wo_lds[1024];         // Wo int8 resident (4KB)
    __shared__ alignas(16) int hbuf[2][64];          // double-buffered h (256 int8)

    const int tid = threadIdx.x;        // 0..511
    const int brow = blockIdx.x;
    const int l   = tid & 63;
    const int wv  = tid >> 6;           // wave 0..7
    const int q   = l & 3;              // k-quarter this lane reads
    const int Q   = wv * 16 + (l >> 2); // global quad id 0..127
    const int obase = Q * 2;            // this quad's 2 outputs
    const int osel  = q & 1;            // lane keeps output obase+osel

    // ---- stage Wi [256x64] -> int8 (scale 8); lane keeps 2 quarter-rows ----
    {
        const float4* wi4 = (const float4*)Wi;
        #pragma unroll
        for (int it = 0; it < 8; ++it) {
            int flat = it * 512 + tid;              // dwords 0..4095
            wstage[flat] = qpack4(wi4[flat], 8.0f, -8.0f, 7.0f);
        }
    }
    __syncthreads();
    int4 wiq[2];   // wiq[i] = Wi[obase+i][q*16 .. +15]
    {
        const int4* p = (const int4*)wstage;
        #pragma unroll
        for (int i = 0; i < 2; ++i) wiq[i] = p[(obase + i) * 4 + q];
    }
    __syncthreads();

    // ---- stage Wr [256x256] -> int8 in two 128-row halves; lane keeps 2 quarter-rows ----
    int4 wr[8];    // wr[i*4+r] = Wr[obase+i][q*64 + r*16 .. +15]
    {
        const float4* wr4 = (const float4*)Wr;
        #pragma unroll
        for (int half = 0; half < 2; ++half) {
            #pragma unroll
            for (int it = 0; it < 16; ++it) {
                int flat = it * 512 + tid;          // dwords 0..8191
                wstage[flat] = qpack4(wr4[half * 8192 + flat], 8.0f, -8.0f, 7.0f);
            }
            __syncthreads();
            if ((obase >> 7) == half) {
                const int4* p = (const int4*)wstage;
                const int ob = obase & 127;
                #pragma unroll
                for (int i = 0; i < 2; ++i)
                    #pragma unroll
                    for (int r = 0; r < 4; ++r)
                        wr[i * 4 + r] = p[(ob + i) * 16 + q * 4 + r];
            }
            __syncthreads();
        }
    }

    // ---- stage Wo [16x256] -> int8, resident ----
    {
        const float4* wo4 = (const float4*)Wo;
        wo_lds[tid]       = qpack4(wo4[tid],       8.0f, -8.0f, 7.0f);
        wo_lds[tid + 512] = qpack4(wo4[tid + 512], 8.0f, -8.0f, 7.0f);
    }

    // ---- stage entire x row to LDS as int8 (scale 128) ----
    {
        const float4* rowf4 = (const float4*)(x + (size_t)brow * (TSEQ * IDIM));
        #pragma unroll 8
        for (int it = 0; it < 32; ++it) {
            int flat = it * 512 + tid;              // float4 idx == packed dword idx
            xlds[flat] = qpack4(rowf4[flat], 128.0f, -128.0f, 127.0f);
        }
    }
    if (tid < 64) hbuf[0][tid] = 0;                 // h0 = 0
    const float bv = bias[obase + osel];
    __syncthreads();

    // u accumulators for t=0
    int u[2];
    {
        const int4 xx = ((const int4*)xlds)[q];
        #pragma unroll
        for (int i = 0; i < 2; ++i) {
            int s = sdot4i8(xx.x, wiq[i].x, 0);
            s = sdot4i8(xx.y, wiq[i].y, s);
            s = sdot4i8(xx.z, wiq[i].z, s);
            u[i] = sdot4i8(xx.w, wiq[i].w, s);
        }
    }

    // ---- main recurrence: 1024 steps, no global traffic, 1 barrier/step ----
    for (int t = 0; t < TSEQ; ++t) {
        // this lane's k-quarter of h_t
        int4 hh[4];
        {
            const int4* hP = (const int4*)hbuf[t & 1];
            #pragma unroll
            for (int r = 0; r < 4; ++r) hh[r] = hP[q * 4 + r];
        }
        // next step's x quarter (pad covers t=1023)
        const int4 xn = ((const int4*)xlds)[(t + 1) * 4 + q];

        // z partials: two chains per output, seeded with u[i]
        int za[2], zb[2];
        #pragma unroll
        for (int i = 0; i < 2; ++i) {
            int s0 = u[i];
            s0 = sdot4i8(hh[0].x, wr[i * 4 + 0].x, s0);
            s0 = sdot4i8(hh[0].y, wr[i * 4 + 0].y, s0);
            s0 = sdot4i8(hh[0].z, wr[i * 4 + 0].z, s0);
            s0 = sdot4i8(hh[0].w, wr[i * 4 + 0].w, s0);
            s0 = sdot4i8(hh[1].x, wr[i * 4 + 1].x, s0);
            s0 = sdot4i8(hh[1].y, wr[i * 4 + 1].y, s0);
            s0 = sdot4i8(hh[1].z, wr[i * 4 + 1].z, s0);
            s0 = sdot4i8(hh[1].w, wr[i * 4 + 1].w, s0);
            int s1 = 0;
            s1 = sdot4i8(hh[2].x, wr[i * 4 + 2].x, s1);
            s1 = sdot4i8(hh[2].y, wr[i * 4 + 2].y, s1);
            s1 = sdot4i8(hh[2].z, wr[i * 4 + 2].z, s1);
            s1 = sdot4i8(hh[2].w, wr[i * 4 + 2].w, s1);
            s1 = sdot4i8(hh[3].x, wr[i * 4 + 3].x, s1);
            s1 = sdot4i8(hh[3].y, wr[i * 4 + 3].y, s1);
            s1 = sdot4i8(hh[3].z, wr[i * 4 + 3].z, s1);
            s1 = sdot4i8(hh[3].w, wr[i * 4 + 3].w, s1);
            za[i] = s0; zb[i] = s1;
        }
        // u for t+1 (h-independent; fills latency bubbles)
        int un[2];
        #pragma unroll
        for (int i = 0; i < 2; ++i) {
            int s = sdot4i8(xn.x, wiq[i].x, 0);
            s = sdot4i8(xn.y, wiq[i].y, s);
            s = sdot4i8(xn.z, wiq[i].z, s);
            un[i] = sdot4i8(xn.w, wiq[i].w, s);
        }

        // quad-reduce both outputs; lane keeps output obase+osel
        const int z0 = qsum(za[0] + zb[0]);
        const int z1 = qsum(za[1] + zb[1]);
        const int z  = osel ? z1 : z0;

        // exact modrelu + 8-bit requantize (fp32 rounding identical to ref)
        const float zf = (float)z;
        const float t1 = fmaf(fabsf(zf), 0.0009765625f, bv);
        const float t2 = fmaxf(t1, 0.0f);
        const float r  = rintf(t2 * 128.0f);
        const int vpos = (int)fminf(r, 127.0f);
        const int vneg = -(int)fminf(r, 128.0f);
        int hv = (z < 0) ? vneg : vpos;
        hv = (z == 0) ? 0 : hv;

        if (q < 2) ((signed char*)hbuf[(t + 1) & 1])[obase + osel] = (signed char)hv;

        u[0] = un[0]; u[1] = un[1];
        __syncthreads();
    }

    // ---- epilogue: out[b, o] = h_1024 . Wo_row(o) / 1024  (h_1024 in hbuf[0]) ----
    if (tid < ODIM) {
        const int4* wo = (const int4*)wo_lds;
        const int4* hl = (const int4*)hbuf[0];
        int a0 = 0, a1 = 0, a2 = 0, a3 = 0;
        #pragma unroll
        for (int i = 0; i < 16; ++i) {
            int4 w4 = wo[tid * 16 + i];
            int4 h4 = hl[i];
            a0 = sdot4i8(h4.x, w4.x, a0);
            a1 = sdot4i8(h4.y, w4.y, a1);
            a2 = sdot4i8(h4.z, w4.z, a2);
            a3 = sdot4i8(h4.w, w4.w, a3);
        }
        out[brow * ODIM + tid] = (float)((a0 + a1) + (a2 + a3)) * 0.0009765625f;
    }
}

extern "C" void kernel_launch(void* const* d_in, const int* in_sizes, int n_in,
                              void* d_out, int out_size, void* d_ws, size_t ws_size,
                              hipStream_t stream) {
    const float* x  = (const float*)d_in[0];   // [B, T, I]
    const float* Wi = (const float*)d_in[1];   // [H, I]
    const float* Wr = (const float*)d_in[2];   // [H, H]
    const float* Wo = (const float*)d_in[3];   // [O, H]
    const float* b  = (const float*)d_in[4];   // [H]
    float* out = (float*)d_out;                // [B, O]

    const int B = in_sizes[0] / (TSEQ * IDIM); // 256
    qornn_kernel<<<B, 512, 0, stream>>>(x, Wi, Wr, Wo, b, out);
}

// Round 6
// 444.153 us; speedup vs baseline: 2.4572x; 1.1567x over previous
//
#include <hip/hip_runtime.h>

// QORNN v6: v3 config (256thr, 1 row/CU, full-x-LDS, quad k-split) + serial-
// path cuts. v5 evidence: extra waves are phase-locked by the per-step barrier
// (occupancy 2x -> dur WORSE); step time is barrier + LDS-burst + read latency
// + dep tail. v6: (1) bv128 fold removes one fp op from the tail (exact:
// pow2 scaling commutes with rne); (2) 4-deep sdot chains (was 8-deep);
// (3) xn-read + u-prefetch moved after the h-write into the barrier shadow,
// shrinking the post-barrier LDS burst to 4 b128/wave.

#define TSEQ 1024
#define IDIM 64
#define HDIM 256
#define ODIM 16

__device__ __forceinline__ int sdot4i8(int a, int b, int c) {
#if __has_builtin(__builtin_amdgcn_sdot4)
    return __builtin_amdgcn_sdot4(a, b, c, false);
#else
    int r = c;
    r += ((a << 24) >> 24) * ((b << 24) >> 24);
    r += ((a << 16) >> 24) * ((b << 16) >> 24);
    r += ((a << 8)  >> 24) * ((b << 8)  >> 24);
    r += (a >> 24) * (b >> 24);
    return r;
#endif
}

__device__ __forceinline__ int qpack4(float4 f, float s, float lo, float hi) {
    int a = (int)fminf(fmaxf(rintf(f.x * s), lo), hi);
    int b = (int)fminf(fmaxf(rintf(f.y * s), lo), hi);
    int c = (int)fminf(fmaxf(rintf(f.z * s), lo), hi);
    int d = (int)fminf(fmaxf(rintf(f.w * s), lo), hi);
    return (a & 255) | ((b & 255) << 8) | ((c & 255) << 16) | ((d & 255) << 24);
}

// quad butterfly sum: all 4 lanes of each quad end with the quad-sum
__device__ __forceinline__ int qsum(int v) {
    v += __builtin_amdgcn_update_dpp(0, v, 0xB1, 0xF, 0xF, true); // quad_perm xor1
    v += __builtin_amdgcn_update_dpp(0, v, 0x4E, 0xF, 0xF, true); // quad_perm xor2
    return v;
}

__global__ __launch_bounds__(256, 1)
void qornn_kernel(const float* __restrict__ x, const float* __restrict__ Wi,
                  const float* __restrict__ Wr, const float* __restrict__ Wo,
                  const float* __restrict__ bias, float* __restrict__ out) {
    __shared__ alignas(16) int xlds[TSEQ * 16 + 16]; // whole row, int8-packed (64KB + pad)
    __shared__ alignas(16) int wstage[8192];         // 32 KB staging; Wo resident after init
    __shared__ alignas(16) int hbuf[2][64];          // double-buffered h (256 int8 each)

    const int tid = threadIdx.x;
    const int brow = blockIdx.x;
    const int l    = tid & 63;
    const int q    = l & 3;             // k-quarter this lane reads
    const int obase = (tid >> 6) * 64 + (l >> 2) * 4; // 4 outputs; obase+q == tid-ish slot

    // ---- stage Wi [256 x 64] fp32 -> int8 (scale 8); lane keeps 4 quarter-rows ----
    {
        const float4* wi4 = (const float4*)Wi;
        #pragma unroll
        for (int it = 0; it < 16; ++it) {
            int flat = it * 256 + tid;
            wstage[flat] = qpack4(wi4[flat], 8.0f, -8.0f, 7.0f);
        }
    }
    __syncthreads();
    int4 wiq[4];   // wiq[i] = Wi[obase+i][q*16 .. q*16+15]
    {
        const int4* p = (const int4*)wstage;
        #pragma unroll
        for (int i = 0; i < 4; ++i) wiq[i] = p[(obase + i) * 4 + q];
    }
    __syncthreads();

    // ---- stage Wr [256 x 256] -> int8 in two halves; lane keeps 4 quarter-rows ----
    int4 wr[16];   // wr[i*4+r] = Wr[obase+i][q*64 + r*16 .. +15]
    {
        const float4* wr4 = (const float4*)Wr;
        #pragma unroll
        for (int it = 0; it < 32; ++it) {
            int flat = it * 256 + tid;
            wstage[flat] = qpack4(wr4[flat], 8.0f, -8.0f, 7.0f);
        }
        __syncthreads();
        if (obase < 128) {
            const int4* p = (const int4*)wstage;
            #pragma unroll
            for (int i = 0; i < 4; ++i)
                #pragma unroll
                for (int r = 0; r < 4; ++r)
                    wr[i * 4 + r] = p[(obase + i) * 16 + q * 4 + r];
        }
        __syncthreads();
        #pragma unroll
        for (int it = 0; it < 32; ++it) {
            int flat = it * 256 + tid;
            wstage[flat] = qpack4(wr4[8192 + flat], 8.0f, -8.0f, 7.0f);
        }
        __syncthreads();
        if (obase >= 128) {
            const int4* p = (const int4*)wstage;
            #pragma unroll
            for (int i = 0; i < 4; ++i)
                #pragma unroll
                for (int r = 0; r < 4; ++r)
                    wr[i * 4 + r] = p[(obase - 128 + i) * 16 + q * 4 + r];
        }
        __syncthreads();
    }

    // ---- stage Wo [16 x 256] -> int8, resident in wstage[0..1023] ----
    {
        const float4* wo4 = (const float4*)Wo;
        #pragma unroll
        for (int it = 0; it < 4; ++it) {
            int flat = it * 256 + tid;
            wstage[flat] = qpack4(wo4[flat], 8.0f, -8.0f, 7.0f);
        }
    }

    // ---- stage entire x row to LDS as int8 (scale 128) ----
    {
        const float4* rowf4 = (const float4*)(x + (size_t)brow * (TSEQ * IDIM));
        #pragma unroll 8
        for (int it = 0; it < 64; ++it) {
            int flat = it * 256 + tid;               // float4 idx == packed dword idx
            xlds[flat] = qpack4(rowf4[flat], 128.0f, -128.0f, 127.0f);
        }
    }
    if (tid < 64) hbuf[0][tid] = 0;                  // h0 = 0
    __syncthreads();

    // bv128 = 128*b (exact pow2 scale); modrelu tail uses |z|*0.125 + bv128
    const float bv128 = bias[tid] * 128.0f;
    const bool qb0 = (q & 1) != 0;
    const bool qb1 = (q & 2) != 0;

    // u accumulators for t=0
    int u[4];
    {
        const int4 xx = ((const int4*)xlds)[q];
        #pragma unroll
        for (int i = 0; i < 4; ++i) {
            int s = sdot4i8(xx.x, wiq[i].x, 0);
            s = sdot4i8(xx.y, wiq[i].y, s);
            s = sdot4i8(xx.z, wiq[i].z, s);
            u[i] = sdot4i8(xx.w, wiq[i].w, s);
        }
    }

    // ---- main recurrence: 1024 steps, no global traffic, 1 barrier/step ----
    #pragma unroll 2
    for (int t = 0; t < TSEQ; ++t) {
        // post-barrier burst: only the 4 h b128 reads
        int4 hh[4];
        {
            const int4* hP = (const int4*)hbuf[t & 1];
            #pragma unroll
            for (int r = 0; r < 4; ++r) hh[r] = hP[q * 4 + r];
        }

        // 4 chains of 4 per output (dep depth 4 + 2 merge); chain0 seeded with u[i]
        int z[4];
        #pragma unroll
        for (int i = 0; i < 4; ++i) {
            int c0 = u[i];
            c0 = sdot4i8(hh[0].x, wr[i * 4 + 0].x, c0);
            c0 = sdot4i8(hh[0].y, wr[i * 4 + 0].y, c0);
            c0 = sdot4i8(hh[0].z, wr[i * 4 + 0].z, c0);
            c0 = sdot4i8(hh[0].w, wr[i * 4 + 0].w, c0);
            int c1 = 0;
            c1 = sdot4i8(hh[1].x, wr[i * 4 + 1].x, c1);
            c1 = sdot4i8(hh[1].y, wr[i * 4 + 1].y, c1);
            c1 = sdot4i8(hh[1].z, wr[i * 4 + 1].z, c1);
            c1 = sdot4i8(hh[1].w, wr[i * 4 + 1].w, c1);
            int c2 = 0;
            c2 = sdot4i8(hh[2].x, wr[i * 4 + 2].x, c2);
            c2 = sdot4i8(hh[2].y, wr[i * 4 + 2].y, c2);
            c2 = sdot4i8(hh[2].z, wr[i * 4 + 2].z, c2);
            c2 = sdot4i8(hh[2].w, wr[i * 4 + 2].w, c2);
            int c3 = 0;
            c3 = sdot4i8(hh[3].x, wr[i * 4 + 3].x, c3);
            c3 = sdot4i8(hh[3].y, wr[i * 4 + 3].y, c3);
            c3 = sdot4i8(hh[3].z, wr[i * 4 + 3].z, c3);
            c3 = sdot4i8(hh[3].w, wr[i * 4 + 3].w, c3);
            z[i] = (c0 + c1) + (c2 + c3);
        }

        // quad-reduce 4 outputs; lane q keeps output obase+q
        const int z0 = qsum(z[0]);
        const int z1 = qsum(z[1]);
        const int z2 = qsum(z[2]);
        const int z3 = qsum(z[3]);
        const int zlo = qb0 ? z1 : z0;
        const int zhi = qb0 ? z3 : z2;
        const int zz  = qb1 ? zhi : zlo;

        // exact modrelu + requantize, bv128-folded (bit-identical to reference):
        // r = rne(max(|z|/8 + 128b, 0)); h = sign(z)*min(r, clip)
        const float zf = (float)zz;
        const float t1 = fmaf(fabsf(zf), 0.125f, bv128);
        const float t2 = fmaxf(t1, 0.0f);
        const float r  = rintf(t2);
        const int vpos = (int)fminf(r, 127.0f);
        const int vneg = -(int)fminf(r, 128.0f);
        int hv = (zz < 0) ? vneg : vpos;
        hv = (zz == 0) ? 0 : hv;

        ((signed char*)hbuf[(t + 1) & 1])[tid] = (signed char)hv;

        // barrier-shadow work: x_{t+1} read + u_{t+1} sdots (h-independent)
        const int4 xn = ((const int4*)xlds)[(t + 1) * 4 + q];   // pad covers t=1023
        #pragma unroll
        for (int i = 0; i < 4; ++i) {
            int s = sdot4i8(xn.x, wiq[i].x, 0);
            s = sdot4i8(xn.y, wiq[i].y, s);
            s = sdot4i8(xn.z, wiq[i].z, s);
            u[i] = sdot4i8(xn.w, wiq[i].w, s);
        }
        __syncthreads();
    }

    // ---- epilogue: out[b, o] = h_1024 . Wo_row(o) / 1024  (h_1024 in hbuf[0]) ----
    if (tid < ODIM) {
        const int4* wo = (const int4*)wstage;
        const int4* hl = (const int4*)hbuf[0];
        int a0 = 0, a1 = 0, a2 = 0, a3 = 0;
        #pragma unroll
        for (int i = 0; i < 16; ++i) {
            int4 w4 = wo[tid * 16 + i];
            int4 h4 = hl[i];
            a0 = sdot4i8(h4.x, w4.x, a0);
            a1 = sdot4i8(h4.y, w4.y, a1);
            a2 = sdot4i8(h4.z, w4.z, a2);
            a3 = sdot4i8(h4.w, w4.w, a3);
        }
        out[brow * ODIM + tid] = (float)((a0 + a1) + (a2 + a3)) * 0.0009765625f;
    }
}

extern "C" void kernel_launch(void* const* d_in, const int* in_sizes, int n_in,
                              void* d_out, int out_size, void* d_ws, size_t ws_size,
                              hipStream_t stream) {
    const float* x  = (const float*)d_in[0];   // [B, T, I]
    const float* Wi = (const float*)d_in[1];   // [H, I]
    const float* Wr = (const float*)d_in[2];   // [H, H]
    const float* Wo = (const float*)d_in[3];   // [O, H]
    const float* b  = (const float*)d_in[4];   // [H]
    float* out = (float*)d_out;                // [B, O]

    const int B = in_sizes[0] / (TSEQ * IDIM); // 256
    qornn_kernel<<<B, HDIM, 0, stream>>>(x, Wi, Wr, Wo, b, out);
}

// Round 7
// 428.316 us; speedup vs baseline: 2.5480x; 1.0370x over previous
//
#include <hip/hip_runtime.h>

// QORNN v7: recurrence dots moved to the MFMA pipe.
// r6 evidence: VALUBusy 58% @ 860cy/step implies v_dot4 is ~4cy/wave ->
// kernel is VALU-throughput-bound on the 80 sdots/lane/step. MFMA pipe is
// idle (MfmaUtil 0). v7: z = h.Wr^T via mfma_i32_16x16x64_i8 with h
// REPLICATED across all 16 A-rows (all C rows identical -> immune to C-row
// mapping and to any consistent A/B k-slot permutation; col=lane&15 is the
// HW-verified part). Per wave: 4 out-tiles x (1 u-mfma + 4 chained h-mfmas)
// = 20 MFMA ~100cy matrix-pipe; VALU only does modrelu+select (~20 instrs).
// u-MFMAs for t+1 issue in the barrier shadow. Exact i32 -> absmax 0.

#define TSEQ 1024
#define IDIM 64
#define HDIM 256
#define ODIM 16

typedef int v4i __attribute__((ext_vector_type(4)));

__device__ __forceinline__ int sdot4i8(int a, int b, int c) {
#if __has_builtin(__builtin_amdgcn_sdot4)
    return __builtin_amdgcn_sdot4(a, b, c, false);
#else
    int r = c;
    r += ((a << 24) >> 24) * ((b << 24) >> 24);
    r += ((a << 16) >> 24) * ((b << 16) >> 24);
    r += ((a << 8)  >> 24) * ((b << 8)  >> 24);
    r += (a >> 24) * (b >> 24);
    return r;
#endif
}

__device__ __forceinline__ int qpack4(float4 f, float s, float lo, float hi) {
    int a = (int)fminf(fmaxf(rintf(f.x * s), lo), hi);
    int b = (int)fminf(fmaxf(rintf(f.y * s), lo), hi);
    int c = (int)fminf(fmaxf(rintf(f.z * s), lo), hi);
    int d = (int)fminf(fmaxf(rintf(f.w * s), lo), hi);
    return (a & 255) | ((b & 255) << 8) | ((c & 255) << 16) | ((d & 255) << 24);
}

__global__ __launch_bounds__(256, 1)
void qornn_kernel(const float* __restrict__ x, const float* __restrict__ Wi,
                  const float* __restrict__ Wr, const float* __restrict__ Wo,
                  const float* __restrict__ bias, float* __restrict__ out) {
    __shared__ alignas(16) int xlds[TSEQ * 16 + 16]; // whole row int8-packed (64KB+pad)
    __shared__ alignas(16) int wstage[8192];         // 32KB weight staging
    __shared__ alignas(16) int wo_lds[1024];         // Wo int8 resident
    __shared__ alignas(16) int hbuf[2][64];          // double-buffered h (256 int8)

    const int tid = threadIdx.x;
    const int brow = blockIdx.x;
    const int w = tid >> 6;        // wave 0..3 -> outputs w*64 .. w*64+63
    const int l = tid & 63;
    const int g = l >> 4;          // lane group 0..3 (k-chunk slot)
    const int n = l & 15;          // col within 16-wide tile

    // ---- stage Wi [256x64] -> int8 (scale 8) ----
    {
        const float4* wi4 = (const float4*)Wi;
        #pragma unroll
        for (int it = 0; it < 16; ++it) {
            int flat = it * 256 + tid;               // dwords 0..4095 (row j = 16 dwords)
            wstage[flat] = qpack4(wi4[flat], 8.0f, -8.0f, 7.0f);
        }
    }
    __syncthreads();
    // B-fragment gather: wiB[t] covers out col (w*64+t*16+n), k-slot g*16..+15
    v4i wiB[4];
    #pragma unroll
    for (int t4 = 0; t4 < 4; ++t4)
        wiB[t4] = *(const v4i*)(wstage + (w * 64 + t4 * 16 + n) * 16 + g * 4);
    __syncthreads();

    // ---- stage Wr [256x256] -> int8 in two 128-row halves; gather B-fragments ----
    v4i wrB[16];   // wrB[t*4+j]: out col (w*64+t*16+n), k = j*64 + g*16 .. +15
    {
        const float4* wr4 = (const float4*)Wr;
        #pragma unroll
        for (int half = 0; half < 2; ++half) {
            #pragma unroll
            for (int it = 0; it < 32; ++it) {
                int flat = it * 256 + tid;           // dwords 0..8191 (row = 64 dwords)
                wstage[flat] = qpack4(wr4[half * 8192 + flat], 8.0f, -8.0f, 7.0f);
            }
            __syncthreads();
            if ((w >> 1) == half) {
                const int rl = (w & 1) * 64;         // local row base in this half
                #pragma unroll
                for (int t4 = 0; t4 < 4; ++t4)
                    #pragma unroll
                    for (int j = 0; j < 4; ++j)
                        wrB[t4 * 4 + j] =
                            *(const v4i*)(wstage + (rl + t4 * 16 + n) * 64 + j * 16 + g * 4);
            }
            __syncthreads();
        }
    }

    // ---- stage Wo [16x256] -> int8, resident ----
    {
        const float4* wo4 = (const float4*)Wo;
        #pragma unroll
        for (int it = 0; it < 4; ++it) {
            int flat = it * 256 + tid;
            wo_lds[flat] = qpack4(wo4[flat], 8.0f, -8.0f, 7.0f);
        }
    }

    // ---- stage entire x row to LDS as int8 (scale 128); h0 = 0 ----
    {
        const float4* rowf4 = (const float4*)(x + (size_t)brow * (TSEQ * IDIM));
        #pragma unroll 8
        for (int it = 0; it < 64; ++it) {
            int flat = it * 256 + tid;
            xlds[flat] = qpack4(rowf4[flat], 128.0f, -128.0f, 127.0f);
        }
    }
    if (tid < 64) hbuf[0][tid] = 0;
    __syncthreads();

    const float bv128 = bias[tid] * 128.0f;          // exact pow2 fold (v6-verified)
    const v4i zero4 = {0, 0, 0, 0};

    // u-MFMAs for t=0 (A = x_0 replicated across rows: value depends only on k-slot)
    v4i accp[4];
    {
        const v4i xA = *(const v4i*)(xlds + g * 4);
        #pragma unroll
        for (int t4 = 0; t4 < 4; ++t4)
            accp[t4] = __builtin_amdgcn_mfma_i32_16x16x64_i8(xA, wiB[t4], zero4, 0, 0, 0);
    }

    // ---- main recurrence: 1024 steps, 1 barrier/step, dots on the MFMA pipe ----
    #pragma unroll 2
    for (int t = 0; t < TSEQ; ++t) {
        // A-fragments of h_t (replicated rows: load depends only on k-slot g)
        const char* hsrc = (const char*)hbuf[t & 1];
        v4i hA[4];
        #pragma unroll
        for (int j = 0; j < 4; ++j)
            hA[j] = *(const v4i*)(hsrc + j * 64 + g * 16);

        v4i acc[4];
        #pragma unroll
        for (int t4 = 0; t4 < 4; ++t4) {
            acc[t4] = accp[t4];
            #pragma unroll
            for (int j = 0; j < 4; ++j)
                acc[t4] = __builtin_amdgcn_mfma_i32_16x16x64_i8(hA[j], wrB[t4 * 4 + j],
                                                                acc[t4], 0, 0, 0);
        }

        // all C rows identical; lane keeps tile g, col n -> output w*64 + g*16 + n == tid
        const int zz = (g == 0) ? acc[0].x : (g == 1) ? acc[1].x
                     : (g == 2) ? acc[2].x : acc[3].x;

        // exact modrelu + requantize (bit-identical to reference; v6-verified fold)
        const float zf = (float)zz;
        const float t1 = fmaf(fabsf(zf), 0.125f, bv128);
        const float t2 = fmaxf(t1, 0.0f);
        const float r  = rintf(t2);
        const int vpos = (int)fminf(r, 127.0f);
        const int vneg = -(int)fminf(r, 128.0f);
        int hv = (zz < 0) ? vneg : vpos;
        hv = (zz == 0) ? 0 : hv;

        ((signed char*)hbuf[(t + 1) & 1])[tid] = (signed char)hv;

        // barrier-shadow: u-MFMAs for t+1 (h-independent; pad covers t=1023)
        const v4i xA = *(const v4i*)(xlds + (t + 1) * 16 + g * 4);
        #pragma unroll
        for (int t4 = 0; t4 < 4; ++t4)
            accp[t4] = __builtin_amdgcn_mfma_i32_16x16x64_i8(xA, wiB[t4], zero4, 0, 0, 0);

        __syncthreads();
    }

    // ---- epilogue: out[b, o] = h_1024 . Wo_row(o) / 1024  (h_1024 in hbuf[0]) ----
    if (tid < ODIM) {
        const int4* wo = (const int4*)wo_lds;
        const int4* hl = (const int4*)hbuf[0];
        int a0 = 0, a1 = 0, a2 = 0, a3 = 0;
        #pragma unroll
        for (int i = 0; i < 16; ++i) {
            int4 w4 = wo[tid * 16 + i];
            int4 h4 = hl[i];
            a0 = sdot4i8(h4.x, w4.x, a0);
            a1 = sdot4i8(h4.y, w4.y, a1);
            a2 = sdot4i8(h4.z, w4.z, a2);
            a3 = sdot4i8(h4.w, w4.w, a3);
        }
        out[brow * ODIM + tid] = (float)((a0 + a1) + (a2 + a3)) * 0.0009765625f;
    }
}

extern "C" void kernel_launch(void* const* d_in, const int* in_sizes, int n_in,
                              void* d_out, int out_size, void* d_ws, size_t ws_size,
                              hipStream_t stream) {
    const float* x  = (const float*)d_in[0];   // [B, T, I]
    const float* Wi = (const float*)d_in[1];   // [H, I]
    const float* Wr = (const float*)d_in[2];   // [H, H]
    const float* Wo = (const float*)d_in[3];   // [O, H]
    const float* b  = (const float*)d_in[4];   // [H]
    float* out = (float*)d_out;                // [B, O]

    const int B = in_sizes[0] / (TSEQ * IDIM); // 256
    qornn_kernel<<<B, HDIM, 0, stream>>>(x, Wi, Wr, Wo, b, out);
}